// Round 3
// baseline (1427.842 us; speedup 1.0000x reference)
//
#include <hip/hip_runtime.h>

typedef unsigned short ushort_t;
typedef unsigned int uint_t;

#define NN 500000
#define NE 1500000
#define BATCH 64
#define LSEQ 512
#define NBLK ((NN + 1023) / 1024)   // 489

__device__ inline float bf2f(ushort_t u) {
    union { uint_t u; float f; } c; c.u = ((uint_t)u) << 16; return c.f;
}
__device__ inline ushort_t f2bf(float f) {
    union { float f; uint_t u; } c; c.f = f;
    uint_t u = c.u;
    return (ushort_t)((u + 0x7fff + ((u >> 16) & 1)) >> 16);  // RNE
}

// ---------------- zero a 4B-word region ----------------
__global__ void k_zero(float* __restrict__ p, int n) {
    int i = blockIdx.x * blockDim.x + threadIdx.x;
    int stride = gridDim.x * blockDim.x;
    for (; i < n; i += stride) p[i] = 0.0f;
}

// ---------------- histogram of dst ----------------
__global__ void k_hist(const int* __restrict__ dst, int* __restrict__ cnt) {
    int e = blockIdx.x * blockDim.x + threadIdx.x;
    if (e < NE) atomicAdd(&cnt[dst[e]], 1);
}

// ---------------- dinv = rsqrt(deg+1) ----------------
__global__ void k_dinv(const int* __restrict__ cnt, float* __restrict__ dinv) {
    int i = blockIdx.x * blockDim.x + threadIdx.x;
    if (i < NN) dinv[i] = rsqrtf((float)cnt[i] + 1.0f);
}

// ---------------- scan: per-block sums (1024 items/block) ----------------
__global__ __launch_bounds__(256) void k_scan_block(const int* __restrict__ cnt, int* __restrict__ bsum) {
    __shared__ int sd[256];
    int blk = blockIdx.x, tid = threadIdx.x;
    int base = blk * 1024 + tid * 4;
    int s = 0;
#pragma unroll
    for (int k = 0; k < 4; ++k) { int i = base + k; if (i < NN) s += cnt[i]; }
    sd[tid] = s;
    __syncthreads();
    for (int off = 128; off; off >>= 1) {
        if (tid < off) sd[tid] += sd[tid + off];
        __syncthreads();
    }
    if (tid == 0) bsum[blk] = sd[0];
}

// ---------------- scan: top-level exclusive scan of block sums ----------------
__global__ __launch_bounds__(512) void k_scan_top(int* __restrict__ bsum) {
    __shared__ int sd[512];
    int tid = threadIdx.x;
    int v = (tid < NBLK) ? bsum[tid] : 0;
    sd[tid] = v;
    __syncthreads();
    for (int off = 1; off < 512; off <<= 1) {
        int t = (tid >= off) ? sd[tid - off] : 0;
        __syncthreads();
        sd[tid] += t;
        __syncthreads();
    }
    if (tid < NBLK) bsum[tid] = sd[tid] - v;  // exclusive
}

// ---------------- scan: finalize rowoff + cursor ----------------
__global__ __launch_bounds__(256) void k_scan_final(const int* __restrict__ cnt, const int* __restrict__ bsum,
                                                    int* __restrict__ rowoff, int* __restrict__ cursor) {
    __shared__ int sd[256];
    int blk = blockIdx.x, tid = threadIdx.x;
    int base = blk * 1024 + tid * 4;
    int loc[4]; int s = 0;
#pragma unroll
    for (int k = 0; k < 4; ++k) { int i = base + k; int c = (i < NN) ? cnt[i] : 0; loc[k] = s; s += c; }
    sd[tid] = s;
    __syncthreads();
    for (int off = 1; off < 256; off <<= 1) {
        int t = (tid >= off) ? sd[tid - off] : 0;
        __syncthreads();
        sd[tid] += t;
        __syncthreads();
    }
    int texc = sd[tid] - s + bsum[blk];
#pragma unroll
    for (int k = 0; k < 4; ++k) {
        int i = base + k;
        if (i < NN) { int v = texc + loc[k]; rowoff[i] = v; cursor[i] = v; }
    }
    if (blk == 0 && tid == 0) rowoff[NN] = NE;
}

// ------- reorder edges into CSR (by dst) + rank-2 layer-1 accumulation -------
__global__ void k_reorder(const int* __restrict__ src, const int* __restrict__ dst,
                          const float* __restrict__ dinv, const float* __restrict__ x,
                          int* __restrict__ cursor, int* __restrict__ esrc,
                          float* __restrict__ ew, float* __restrict__ acc2) {
    int e = blockIdx.x * blockDim.x + threadIdx.x;
    if (e >= NE) return;
    int s = src[e], d = dst[e];
    float w = dinv[s] * dinv[d];
    int pos = atomicAdd(&cursor[d], 1);
    esrc[pos] = s;
    ew[pos] = w;
    atomicAdd(&acc2[2 * d],     w * x[2 * s]);
    atomicAdd(&acc2[2 * d + 1], w * x[2 * s + 1]);
}

// ------- layer-1 dense build: h1 = dv^2*(x@W1) + (acc2@W1) + b1  (pre-relu, bf16) -------
__global__ void k_build1(const float* __restrict__ x, const float* __restrict__ W1,
                         const float* __restrict__ b1, const float* __restrict__ dinv,
                         const float* __restrict__ acc2, ushort_t* __restrict__ h1) {
    int lane = threadIdx.x & 63;
    int wave = (blockIdx.x * blockDim.x + threadIdx.x) >> 6;
    int nwaves = (gridDim.x * blockDim.x) >> 6;
    float w0 = W1[lane], w1 = W1[64 + lane], bj = b1[lane];
    for (int n = wave; n < NN; n += nwaves) {
        float dv = dinv[n];
        float c0 = dv * dv * x[2 * n]     + acc2[2 * n];
        float c1 = dv * dv * x[2 * n + 1] + acc2[2 * n + 1];
        h1[(size_t)n * 64 + lane] = f2bf(c0 * w0 + c1 * w1 + bj);
    }
}

// ------- layer 2 matvec: xw2 = relu(h1) @ W2  (bf16 out) -------
__global__ void k_gemm2(const ushort_t* __restrict__ h1, const float* __restrict__ W2,
                        ushort_t* __restrict__ xw2) {
    int lane = threadIdx.x & 63;
    int wave = (blockIdx.x * blockDim.x + threadIdx.x) >> 6;
    int nwaves = (gridDim.x * blockDim.x) >> 6;
    float wcol[64];
#pragma unroll
    for (int k = 0; k < 64; ++k) wcol[k] = W2[k * 64 + lane];
    for (int n = wave; n < NN; n += nwaves) {
        const uint4* hp = (const uint4*)(h1 + (size_t)n * 64);  // 8 x (8 bf16)
        float acc = 0.0f;
#pragma unroll
        for (int kk = 0; kk < 8; ++kk) {
            uint4 u = hp[kk];
            uint_t us[4] = {u.x, u.y, u.z, u.w};
#pragma unroll
            for (int j = 0; j < 4; ++j) {
                float lo = __uint_as_float(us[j] << 16);
                float hi = __uint_as_float(us[j] & 0xffff0000u);
                acc += fmaxf(lo, 0.0f) * wcol[8 * kk + 2 * j]
                     + fmaxf(hi, 0.0f) * wcol[8 * kk + 2 * j + 1];
            }
        }
        xw2[(size_t)n * 64 + lane] = f2bf(acc);
    }
}

// ------- layer-2 CSR aggregate + relu + pool atomics (fused) -------
__global__ void k_aggpool(const ushort_t* __restrict__ xw2, const float* __restrict__ b2,
                          const float* __restrict__ dinv, const int* __restrict__ rowoff,
                          const int* __restrict__ esrc, const float* __restrict__ ew,
                          const int* __restrict__ batch, const int* __restrict__ depth,
                          float* __restrict__ sumb, uint_t* __restrict__ mxb,
                          float* __restrict__ cntb) {
    int lane = threadIdx.x & 63;
    int wave = (blockIdx.x * blockDim.x + threadIdx.x) >> 6;
    int nwaves = (gridDim.x * blockDim.x) >> 6;
    float bj = b2[lane];
    for (int n = wave; n < NN; n += nwaves) {
        float dv = dinv[n];
        float acc = dv * dv * bf2f(xw2[(size_t)n * 64 + lane]) + bj;
        int r0 = rowoff[n], r1 = rowoff[n + 1];
        for (int i = r0; i < r1; ++i) {
            int s = esrc[i];
            float w = ew[i];
            acc += w * bf2f(xw2[(size_t)s * 64 + lane]);
        }
        float v = fmaxf(acc, 0.0f);
        int seg = batch[n] * LSEQ + depth[n];
        atomicAdd(&sumb[seg * 64 + lane], v);
        atomicMax(&mxb[seg * 64 + lane], __float_as_uint(v));  // v >= 0
        if (lane == 0) atomicAdd(&cntb[seg], 1.0f);
    }
}

// ---------------- conv1d(k=3,pad=1) + relu + partial mean over L ----------------
__global__ __launch_bounds__(256) void k_conv(const float* __restrict__ sum,
                                              const float* __restrict__ mxf,
                                              const float* __restrict__ cnt,
                                              const float* __restrict__ cw,
                                              const float* __restrict__ cb,
                                              float* __restrict__ pooled) {
    __shared__ float s_seq[66 * 129];
    int b = blockIdx.x >> 3;
    int l0 = (blockIdx.x & 7) * 64;
    int tid = threadIdx.x;
    for (int idx = tid; idx < 66 * 128; idx += 256) {
        int r = idx >> 7, i = idx & 127;
        int l = l0 + r - 1;
        float v = 0.0f;
        if (l >= 0 && l < LSEQ) {
            int seg = b * LSEQ + l;
            if (i < 64) v = sum[seg * 64 + i] / fmaxf(cnt[seg], 1.0f);
            else        v = mxf[seg * 64 + (i - 64)];
        }
        s_seq[r * 129 + i] = v;
    }
    __syncthreads();
    int l_local = tid & 63;
    int wid = tid >> 6;
    for (int rep = 0; rep < 16; ++rep) {
        int c = __builtin_amdgcn_readfirstlane(wid + 4 * rep);
        const float* wc = cw + c * 384;
        float acc = cb[c];
#pragma unroll
        for (int kk = 0; kk < 3; ++kk) {
            const float* sr = s_seq + (l_local + kk) * 129;
#pragma unroll 8
            for (int i = 0; i < 128; ++i)
                acc += sr[i] * wc[i * 3 + kk];
        }
        float y = fmaxf(acc, 0.0f);
#pragma unroll
        for (int off = 32; off; off >>= 1) y += __shfl_xor(y, off, 64);
        if (l_local == 0) atomicAdd(&pooled[b * 64 + c], y);
    }
}

// ---------------- head ----------------
__global__ void k_head(const float* __restrict__ pooled, const float* __restrict__ f1w,
                       const float* __restrict__ f1b, const float* __restrict__ f2w,
                       const float* __restrict__ f2b, float* __restrict__ out) {
    int b = blockIdx.x;
    int j = threadIdx.x;
    const float invL = 1.0f / (float)LSEQ;
    float z = f1b[j];
    for (int c = 0; c < 64; ++c)
        z += (pooled[b * 64 + c] * invL) * f1w[c * 64 + j];
    z = fmaxf(z, 0.0f);
    float v = z * f2w[j];
#pragma unroll
    for (int off = 32; off; off >>= 1) v += __shfl_xor(v, off, 64);
    if (j == 0) out[b] = 1.0f / (1.0f + expf(-(v + f2b[0])));
}

extern "C" void kernel_launch(void* const* d_in, const int* in_sizes, int n_in,
                              void* d_out, int out_size, void* d_ws, size_t ws_size,
                              hipStream_t stream) {
    const float* x     = (const float*)d_in[0];
    const int*   ei    = (const int*)d_in[1];
    const int*   depth = (const int*)d_in[2];
    const int*   batch = (const int*)d_in[3];
    const float* W1    = (const float*)d_in[4];
    const float* b1    = (const float*)d_in[5];
    const float* W2    = (const float*)d_in[6];
    const float* b2    = (const float*)d_in[7];
    const float* cw    = (const float*)d_in[8];
    const float* cb    = (const float*)d_in[9];
    const float* f1w   = (const float*)d_in[10];
    const float* f1b   = (const float*)d_in[11];
    const float* f2w   = (const float*)d_in[12];
    const float* f2b   = (const float*)d_in[13];
    float* out = (float*)d_out;

    // ---- workspace layout (~169 MB, all 16B-aligned chunks) ----
    char* p = (char*)d_ws;
    int*      cnt    = (int*)p;        p += (size_t)NN * 4;
    float*    acc2   = (float*)p;      p += (size_t)NN * 8;        // contiguous after cnt (zeroed together)
    int*      rowoff = (int*)p;        p += (size_t)(NN + 8) * 4;
    int*      cursor = (int*)p;        p += (size_t)NN * 4;
    float*    dinv   = (float*)p;      p += (size_t)NN * 4;
    int*      esrc   = (int*)p;        p += (size_t)NE * 4;
    float*    ew     = (float*)p;      p += (size_t)NE * 4;
    ushort_t* h1     = (ushort_t*)p;   p += (size_t)NN * 128;
    ushort_t* xw2    = (ushort_t*)p;   p += (size_t)NN * 128;
    float*    sumb   = (float*)p;      p += (size_t)BATCH * LSEQ * 64 * 4;
    uint_t*   mxb    = (uint_t*)p;     p += (size_t)BATCH * LSEQ * 64 * 4;
    float*    cntb   = (float*)p;      p += (size_t)BATCH * LSEQ * 4;
    float*    pool   = (float*)p;      p += (size_t)BATCH * 64 * 4;
    int*      bsum   = (int*)p;        // NBLK ints

    const int* src = ei;
    const int* dst = ei + NE;

    // zero: cnt+acc2 (3*NN words) and pool-state region
    k_zero<<<1024, 256, 0, stream>>>((float*)cnt, 3 * NN);
    int zn2 = BATCH * LSEQ * 64 * 2 + BATCH * LSEQ + BATCH * 64;
    k_zero<<<1024, 256, 0, stream>>>(sumb, zn2);

    // degree histogram -> dinv; CSR offsets
    k_hist<<<(NE + 255) / 256, 256, 0, stream>>>(dst, cnt);
    k_dinv<<<(NN + 255) / 256, 256, 0, stream>>>(cnt, dinv);
    k_scan_block<<<NBLK, 256, 0, stream>>>(cnt, bsum);
    k_scan_top<<<1, 512, 0, stream>>>(bsum);
    k_scan_final<<<NBLK, 256, 0, stream>>>(cnt, bsum, rowoff, cursor);

    // CSR reorder + rank-2 layer-1 scatter (2 floats/edge)
    k_reorder<<<(NE + 255) / 256, 256, 0, stream>>>(src, dst, dinv, x, cursor, esrc, ew, acc2);

    // layer-1 dense build (bf16 h1, pre-relu)
    k_build1<<<2048, 256, 0, stream>>>(x, W1, b1, dinv, acc2, h1);

    // layer-2 matvec (bf16 xw2)
    k_gemm2<<<2048, 256, 0, stream>>>(h1, W2, xw2);

    // layer-2 CSR aggregate + relu + pool (fused)
    k_aggpool<<<2048, 256, 0, stream>>>(xw2, b2, dinv, rowoff, esrc, ew, batch, depth,
                                        sumb, mxb, cntb);

    // conv + partial mean
    k_conv<<<BATCH * 8, 256, 0, stream>>>(sumb, (const float*)mxb, cntb, cw, cb, pool);

    // head
    k_head<<<BATCH, 64, 0, stream>>>(pool, f1w, f1b, f2w, f2b, out);
}

// Round 4
// 1122.481 us; speedup vs baseline: 1.2720x; 1.2720x over previous
//
#include <hip/hip_runtime.h>

typedef unsigned short ushort_t;
typedef unsigned int uint_t;

#define NN 500000
#define NE 1500000
#define BATCH 64
#define LSEQ 512
#define NBLK ((NN + 1023) / 1024)   // 489

__device__ inline float bf2f(ushort_t u) {
    union { uint_t u; float f; } c; c.u = ((uint_t)u) << 16; return c.f;
}
__device__ inline ushort_t f2bf(float f) {
    union { float f; uint_t u; } c; c.f = f;
    uint_t u = c.u;
    return (ushort_t)((u + 0x7fff + ((u >> 16) & 1)) >> 16);  // RNE
}

// ---------------- zero a 4B-word region ----------------
__global__ void k_zero(float* __restrict__ p, int n) {
    int i = blockIdx.x * blockDim.x + threadIdx.x;
    int stride = gridDim.x * blockDim.x;
    for (; i < n; i += stride) p[i] = 0.0f;
}

// ---------------- histogram of dst ----------------
__global__ void k_hist(const int* __restrict__ dst, int* __restrict__ cnt) {
    int e = blockIdx.x * blockDim.x + threadIdx.x;
    if (e < NE) atomicAdd(&cnt[dst[e]], 1);
}

// ---------------- dinv = rsqrt(deg+1) ----------------
__global__ void k_dinv(const int* __restrict__ cnt, float* __restrict__ dinv) {
    int i = blockIdx.x * blockDim.x + threadIdx.x;
    if (i < NN) dinv[i] = rsqrtf((float)cnt[i] + 1.0f);
}

// ---------------- scan: per-block sums (1024 items/block) ----------------
__global__ __launch_bounds__(256) void k_scan_block(const int* __restrict__ cnt, int* __restrict__ bsum) {
    __shared__ int sd[256];
    int blk = blockIdx.x, tid = threadIdx.x;
    int base = blk * 1024 + tid * 4;
    int s = 0;
#pragma unroll
    for (int k = 0; k < 4; ++k) { int i = base + k; if (i < NN) s += cnt[i]; }
    sd[tid] = s;
    __syncthreads();
    for (int off = 128; off; off >>= 1) {
        if (tid < off) sd[tid] += sd[tid + off];
        __syncthreads();
    }
    if (tid == 0) bsum[blk] = sd[0];
}

// ---------------- scan: top-level exclusive scan of block sums ----------------
__global__ __launch_bounds__(512) void k_scan_top(int* __restrict__ bsum) {
    __shared__ int sd[512];
    int tid = threadIdx.x;
    int v = (tid < NBLK) ? bsum[tid] : 0;
    sd[tid] = v;
    __syncthreads();
    for (int off = 1; off < 512; off <<= 1) {
        int t = (tid >= off) ? sd[tid - off] : 0;
        __syncthreads();
        sd[tid] += t;
        __syncthreads();
    }
    if (tid < NBLK) bsum[tid] = sd[tid] - v;  // exclusive
}

// ---------------- scan: finalize rowoff + cursor ----------------
__global__ __launch_bounds__(256) void k_scan_final(const int* __restrict__ cnt, const int* __restrict__ bsum,
                                                    int* __restrict__ rowoff, int* __restrict__ cursor) {
    __shared__ int sd[256];
    int blk = blockIdx.x, tid = threadIdx.x;
    int base = blk * 1024 + tid * 4;
    int loc[4]; int s = 0;
#pragma unroll
    for (int k = 0; k < 4; ++k) { int i = base + k; int c = (i < NN) ? cnt[i] : 0; loc[k] = s; s += c; }
    sd[tid] = s;
    __syncthreads();
    for (int off = 1; off < 256; off <<= 1) {
        int t = (tid >= off) ? sd[tid - off] : 0;
        __syncthreads();
        sd[tid] += t;
        __syncthreads();
    }
    int texc = sd[tid] - s + bsum[blk];
#pragma unroll
    for (int k = 0; k < 4; ++k) {
        int i = base + k;
        if (i < NN) { int v = texc + loc[k]; rowoff[i] = v; cursor[i] = v; }
    }
    if (blk == 0 && tid == 0) rowoff[NN] = NE;
}

// ------- reorder edges into CSR (by dst) + rank-2 layer-1 accumulation -------
__global__ void k_reorder(const int* __restrict__ src, const int* __restrict__ dst,
                          const float* __restrict__ dinv, const float* __restrict__ x,
                          int* __restrict__ cursor, int* __restrict__ esrc,
                          float* __restrict__ ew, float* __restrict__ acc2) {
    int e = blockIdx.x * blockDim.x + threadIdx.x;
    if (e >= NE) return;
    int s = src[e], d = dst[e];
    float w = dinv[s] * dinv[d];
    int pos = atomicAdd(&cursor[d], 1);
    esrc[pos] = s;
    ew[pos] = w;
    atomicAdd(&acc2[2 * d],     w * x[2 * s]);
    atomicAdd(&acc2[2 * d + 1], w * x[2 * s + 1]);
}

// ------- layer-1 dense build: h1 = dv^2*(x@W1) + (acc2@W1) + b1  (pre-relu, bf16) -------
__global__ void k_build1(const float* __restrict__ x, const float* __restrict__ W1,
                         const float* __restrict__ b1, const float* __restrict__ dinv,
                         const float* __restrict__ acc2, ushort_t* __restrict__ h1) {
    int lane = threadIdx.x & 63;
    int wave = (blockIdx.x * blockDim.x + threadIdx.x) >> 6;
    int nwaves = (gridDim.x * blockDim.x) >> 6;
    float w0 = W1[lane], w1 = W1[64 + lane], bj = b1[lane];
    for (int n = wave; n < NN; n += nwaves) {
        float dv = dinv[n];
        float c0 = dv * dv * x[2 * n]     + acc2[2 * n];
        float c1 = dv * dv * x[2 * n + 1] + acc2[2 * n + 1];
        h1[(size_t)n * 64 + lane] = f2bf(c0 * w0 + c1 * w1 + bj);
    }
}

// ------- layer 2 matvec: xw2 = relu(h1) @ W2  (bf16 out) -------
// lane = output col j. W2 columns are re-read from L1 each chunk (16 KB, L1-resident)
// instead of a per-lane wcol[64] array (which spilled to scratch: 2 GB FETCH in r3).
__global__ void k_gemm2(const ushort_t* __restrict__ h1, const float* __restrict__ W2,
                        ushort_t* __restrict__ xw2) {
    int lane = threadIdx.x & 63;
    int wave = (blockIdx.x * blockDim.x + threadIdx.x) >> 6;
    int nwaves = (gridDim.x * blockDim.x) >> 6;
    for (int n = wave; n < NN; n += nwaves) {
        const uint4* hp = (const uint4*)(h1 + (size_t)n * 64);  // 8 x (8 bf16), wave-uniform
        float acc = 0.0f;
        for (int c = 0; c < 8; ++c) {       // 8 k-values per chunk; no big unroll -> no spill
            uint4 u = hp[c];
            const float* wp = W2 + (c * 8) * 64 + lane;
            float h0 = fmaxf(__uint_as_float(u.x << 16), 0.0f);
            float h1v = fmaxf(__uint_as_float(u.x & 0xffff0000u), 0.0f);
            float h2 = fmaxf(__uint_as_float(u.y << 16), 0.0f);
            float h3 = fmaxf(__uint_as_float(u.y & 0xffff0000u), 0.0f);
            float h4 = fmaxf(__uint_as_float(u.z << 16), 0.0f);
            float h5 = fmaxf(__uint_as_float(u.z & 0xffff0000u), 0.0f);
            float h6 = fmaxf(__uint_as_float(u.w << 16), 0.0f);
            float h7 = fmaxf(__uint_as_float(u.w & 0xffff0000u), 0.0f);
            acc += h0 * wp[0]       + h1v * wp[64]
                 + h2 * wp[2 * 64]  + h3 * wp[3 * 64]
                 + h4 * wp[4 * 64]  + h5 * wp[5 * 64]
                 + h6 * wp[6 * 64]  + h7 * wp[7 * 64];
        }
        xw2[(size_t)n * 64 + lane] = f2bf(acc);
    }
}

// ------- layer-2 CSR aggregate + relu + pool atomics (fused) -------
__global__ void k_aggpool(const ushort_t* __restrict__ xw2, const float* __restrict__ b2,
                          const float* __restrict__ dinv, const int* __restrict__ rowoff,
                          const int* __restrict__ esrc, const float* __restrict__ ew,
                          const int* __restrict__ batch, const int* __restrict__ depth,
                          float* __restrict__ sumb, uint_t* __restrict__ mxb,
                          float* __restrict__ cntb) {
    int lane = threadIdx.x & 63;
    int wave = (blockIdx.x * blockDim.x + threadIdx.x) >> 6;
    int nwaves = (gridDim.x * blockDim.x) >> 6;
    float bj = b2[lane];
    for (int n = wave; n < NN; n += nwaves) {
        float dv = dinv[n];
        float acc = dv * dv * bf2f(xw2[(size_t)n * 64 + lane]) + bj;
        int r0 = rowoff[n], r1 = rowoff[n + 1];
        for (int i = r0; i < r1; ++i) {
            int s = esrc[i];
            float w = ew[i];
            acc += w * bf2f(xw2[(size_t)s * 64 + lane]);
        }
        float v = fmaxf(acc, 0.0f);
        int seg = batch[n] * LSEQ + depth[n];
        atomicAdd(&sumb[seg * 64 + lane], v);
        atomicMax(&mxb[seg * 64 + lane], __float_as_uint(v));  // v >= 0
        if (lane == 0) atomicAdd(&cntb[seg], 1.0f);
    }
}

// ---------------- conv1d(k=3,pad=1) + relu + partial mean over L ----------------
__global__ __launch_bounds__(256) void k_conv(const float* __restrict__ sum,
                                              const float* __restrict__ mxf,
                                              const float* __restrict__ cnt,
                                              const float* __restrict__ cw,
                                              const float* __restrict__ cb,
                                              float* __restrict__ pooled) {
    __shared__ float s_seq[66 * 129];
    int b = blockIdx.x >> 3;
    int l0 = (blockIdx.x & 7) * 64;
    int tid = threadIdx.x;
    for (int idx = tid; idx < 66 * 128; idx += 256) {
        int r = idx >> 7, i = idx & 127;
        int l = l0 + r - 1;
        float v = 0.0f;
        if (l >= 0 && l < LSEQ) {
            int seg = b * LSEQ + l;
            if (i < 64) v = sum[seg * 64 + i] / fmaxf(cnt[seg], 1.0f);
            else        v = mxf[seg * 64 + (i - 64)];
        }
        s_seq[r * 129 + i] = v;
    }
    __syncthreads();
    int l_local = tid & 63;
    int wid = tid >> 6;
    for (int rep = 0; rep < 16; ++rep) {
        int c = __builtin_amdgcn_readfirstlane(wid + 4 * rep);
        const float* wc = cw + c * 384;
        float acc = cb[c];
#pragma unroll
        for (int kk = 0; kk < 3; ++kk) {
            const float* sr = s_seq + (l_local + kk) * 129;
#pragma unroll 8
            for (int i = 0; i < 128; ++i)
                acc += sr[i] * wc[i * 3 + kk];
        }
        float y = fmaxf(acc, 0.0f);
#pragma unroll
        for (int off = 32; off; off >>= 1) y += __shfl_xor(y, off, 64);
        if (l_local == 0) atomicAdd(&pooled[b * 64 + c], y);
    }
}

// ---------------- head ----------------
__global__ void k_head(const float* __restrict__ pooled, const float* __restrict__ f1w,
                       const float* __restrict__ f1b, const float* __restrict__ f2w,
                       const float* __restrict__ f2b, float* __restrict__ out) {
    int b = blockIdx.x;
    int j = threadIdx.x;
    const float invL = 1.0f / (float)LSEQ;
    float z = f1b[j];
    for (int c = 0; c < 64; ++c)
        z += (pooled[b * 64 + c] * invL) * f1w[c * 64 + j];
    z = fmaxf(z, 0.0f);
    float v = z * f2w[j];
#pragma unroll
    for (int off = 32; off; off >>= 1) v += __shfl_xor(v, off, 64);
    if (j == 0) out[b] = 1.0f / (1.0f + expf(-(v + f2b[0])));
}

extern "C" void kernel_launch(void* const* d_in, const int* in_sizes, int n_in,
                              void* d_out, int out_size, void* d_ws, size_t ws_size,
                              hipStream_t stream) {
    const float* x     = (const float*)d_in[0];
    const int*   ei    = (const int*)d_in[1];
    const int*   depth = (const int*)d_in[2];
    const int*   batch = (const int*)d_in[3];
    const float* W1    = (const float*)d_in[4];
    const float* b1    = (const float*)d_in[5];
    const float* W2    = (const float*)d_in[6];
    const float* b2    = (const float*)d_in[7];
    const float* cw    = (const float*)d_in[8];
    const float* cb    = (const float*)d_in[9];
    const float* f1w   = (const float*)d_in[10];
    const float* f1b   = (const float*)d_in[11];
    const float* f2w   = (const float*)d_in[12];
    const float* f2b   = (const float*)d_in[13];
    float* out = (float*)d_out;

    // ---- workspace layout (~169 MB, all 16B-aligned chunks) ----
    char* p = (char*)d_ws;
    int*      cnt    = (int*)p;        p += (size_t)NN * 4;
    float*    acc2   = (float*)p;      p += (size_t)NN * 8;
    int*      rowoff = (int*)p;        p += (size_t)(NN + 8) * 4;
    int*      cursor = (int*)p;        p += (size_t)NN * 4;
    float*    dinv   = (float*)p;      p += (size_t)NN * 4;
    int*      esrc   = (int*)p;        p += (size_t)NE * 4;
    float*    ew     = (float*)p;      p += (size_t)NE * 4;
    ushort_t* h1     = (ushort_t*)p;   p += (size_t)NN * 128;
    ushort_t* xw2    = (ushort_t*)p;   p += (size_t)NN * 128;
    float*    sumb   = (float*)p;      p += (size_t)BATCH * LSEQ * 64 * 4;
    uint_t*   mxb    = (uint_t*)p;     p += (size_t)BATCH * LSEQ * 64 * 4;
    float*    cntb   = (float*)p;      p += (size_t)BATCH * LSEQ * 4;
    float*    pool   = (float*)p;      p += (size_t)BATCH * 64 * 4;
    int*      bsum   = (int*)p;        // NBLK ints

    const int* src = ei;
    const int* dst = ei + NE;

    // zero: cnt+acc2 (3*NN words) and pool-state region
    k_zero<<<1024, 256, 0, stream>>>((float*)cnt, 3 * NN);
    int zn2 = BATCH * LSEQ * 64 * 2 + BATCH * LSEQ + BATCH * 64;
    k_zero<<<1024, 256, 0, stream>>>(sumb, zn2);

    // degree histogram -> dinv; CSR offsets
    k_hist<<<(NE + 255) / 256, 256, 0, stream>>>(dst, cnt);
    k_dinv<<<(NN + 255) / 256, 256, 0, stream>>>(cnt, dinv);
    k_scan_block<<<NBLK, 256, 0, stream>>>(cnt, bsum);
    k_scan_top<<<1, 512, 0, stream>>>(bsum);
    k_scan_final<<<NBLK, 256, 0, stream>>>(cnt, bsum, rowoff, cursor);

    // CSR reorder + rank-2 layer-1 scatter (2 floats/edge)
    k_reorder<<<(NE + 255) / 256, 256, 0, stream>>>(src, dst, dinv, x, cursor, esrc, ew, acc2);

    // layer-1 dense build (bf16 h1, pre-relu)
    k_build1<<<2048, 256, 0, stream>>>(x, W1, b1, dinv, acc2, h1);

    // layer-2 matvec (bf16 xw2)
    k_gemm2<<<2048, 256, 0, stream>>>(h1, W2, xw2);

    // layer-2 CSR aggregate + relu + pool (fused)
    k_aggpool<<<2048, 256, 0, stream>>>(xw2, b2, dinv, rowoff, esrc, ew, batch, depth,
                                        sumb, mxb, cntb);

    // conv + partial mean
    k_conv<<<BATCH * 8, 256, 0, stream>>>(sumb, (const float*)mxb, cntb, cw, cb, pool);

    // head
    k_head<<<BATCH, 64, 0, stream>>>(pool, f1w, f1b, f2w, f2b, out);
}

// Round 5
// 794.578 us; speedup vs baseline: 1.7970x; 1.4127x over previous
//
#include <hip/hip_runtime.h>

typedef unsigned short ushort_t;
typedef unsigned int uint_t;
typedef __attribute__((ext_vector_type(8))) short short8;
typedef __attribute__((ext_vector_type(4))) float f32x4;

#define NN 500000
#define NE 1500000
#define BATCH 64
#define LSEQ 512
#define NBLK ((NN + 1023) / 1024)   // 489

__device__ inline float bf2f(ushort_t u) {
    union { uint_t u; float f; } c; c.u = ((uint_t)u) << 16; return c.f;
}
__device__ inline ushort_t f2bf(float f) {
    union { float f; uint_t u; } c; c.f = f;
    uint_t u = c.u;
    return (ushort_t)((u + 0x7fff + ((u >> 16) & 1)) >> 16);  // RNE
}

// ---------------- zero a 4B-word region ----------------
__global__ void k_zero(float* __restrict__ p, int n) {
    int i = blockIdx.x * blockDim.x + threadIdx.x;
    int stride = gridDim.x * blockDim.x;
    for (; i < n; i += stride) p[i] = 0.0f;
}

// ---------------- histogram of dst ----------------
__global__ void k_hist(const int* __restrict__ dst, int* __restrict__ cnt) {
    int e = blockIdx.x * blockDim.x + threadIdx.x;
    if (e < NE) atomicAdd(&cnt[dst[e]], 1);
}

// ---------------- dinv = rsqrt(deg+1) ----------------
__global__ void k_dinv(const int* __restrict__ cnt, float* __restrict__ dinv) {
    int i = blockIdx.x * blockDim.x + threadIdx.x;
    if (i < NN) dinv[i] = rsqrtf((float)cnt[i] + 1.0f);
}

// ---------------- W2 -> bf16 ----------------
__global__ void k_w2bf(const float* __restrict__ W2, ushort_t* __restrict__ W2b) {
    int i = blockIdx.x * blockDim.x + threadIdx.x;
    if (i < 64 * 64) W2b[i] = f2bf(W2[i]);
}

// ---------------- scan: per-block sums (1024 items/block) ----------------
__global__ __launch_bounds__(256) void k_scan_block(const int* __restrict__ cnt, int* __restrict__ bsum) {
    __shared__ int sd[256];
    int blk = blockIdx.x, tid = threadIdx.x;
    int base = blk * 1024 + tid * 4;
    int s = 0;
#pragma unroll
    for (int k = 0; k < 4; ++k) { int i = base + k; if (i < NN) s += cnt[i]; }
    sd[tid] = s;
    __syncthreads();
    for (int off = 128; off; off >>= 1) {
        if (tid < off) sd[tid] += sd[tid + off];
        __syncthreads();
    }
    if (tid == 0) bsum[blk] = sd[0];
}

// ---------------- scan: top-level exclusive scan of block sums ----------------
__global__ __launch_bounds__(512) void k_scan_top(int* __restrict__ bsum) {
    __shared__ int sd[512];
    int tid = threadIdx.x;
    int v = (tid < NBLK) ? bsum[tid] : 0;
    sd[tid] = v;
    __syncthreads();
    for (int off = 1; off < 512; off <<= 1) {
        int t = (tid >= off) ? sd[tid - off] : 0;
        __syncthreads();
        sd[tid] += t;
        __syncthreads();
    }
    if (tid < NBLK) bsum[tid] = sd[tid] - v;  // exclusive
}

// ---------------- scan: finalize rowoff + cursor ----------------
__global__ __launch_bounds__(256) void k_scan_final(const int* __restrict__ cnt, const int* __restrict__ bsum,
                                                    int* __restrict__ rowoff, int* __restrict__ cursor) {
    __shared__ int sd[256];
    int blk = blockIdx.x, tid = threadIdx.x;
    int base = blk * 1024 + tid * 4;
    int loc[4]; int s = 0;
#pragma unroll
    for (int k = 0; k < 4; ++k) { int i = base + k; int c = (i < NN) ? cnt[i] : 0; loc[k] = s; s += c; }
    sd[tid] = s;
    __syncthreads();
    for (int off = 1; off < 256; off <<= 1) {
        int t = (tid >= off) ? sd[tid - off] : 0;
        __syncthreads();
        sd[tid] += t;
        __syncthreads();
    }
    int texc = sd[tid] - s + bsum[blk];
#pragma unroll
    for (int k = 0; k < 4; ++k) {
        int i = base + k;
        if (i < NN) { int v = texc + loc[k]; rowoff[i] = v; cursor[i] = v; }
    }
    if (blk == 0 && tid == 0) rowoff[NN] = NE;
}

// ------- reorder edges into CSR (by dst) + rank-2 layer-1 accumulation -------
__global__ void k_reorder(const int* __restrict__ src, const int* __restrict__ dst,
                          const float* __restrict__ dinv, const float* __restrict__ x,
                          int* __restrict__ cursor, int* __restrict__ esrc,
                          float* __restrict__ ew, float* __restrict__ acc2) {
    int e = blockIdx.x * blockDim.x + threadIdx.x;
    if (e >= NE) return;
    int s = src[e], d = dst[e];
    float w = dinv[s] * dinv[d];
    int pos = atomicAdd(&cursor[d], 1);
    esrc[pos] = s;
    ew[pos] = w;
    atomicAdd(&acc2[2 * d],     w * x[2 * s]);
    atomicAdd(&acc2[2 * d + 1], w * x[2 * s + 1]);
}

// ------- layer-1 dense build: h1 = relu(dv^2*(x@W1) + (acc2@W1) + b1)  (bf16) -------
__global__ void k_build1(const float* __restrict__ x, const float* __restrict__ W1,
                         const float* __restrict__ b1, const float* __restrict__ dinv,
                         const float* __restrict__ acc2, ushort_t* __restrict__ h1) {
    int lane = threadIdx.x & 63;
    int wave = (blockIdx.x * blockDim.x + threadIdx.x) >> 6;
    int nwaves = (gridDim.x * blockDim.x) >> 6;
    float w0 = W1[lane], w1 = W1[64 + lane], bj = b1[lane];
    for (int n = wave; n < NN; n += nwaves) {
        float dv = dinv[n];
        float c0 = dv * dv * x[2 * n]     + acc2[2 * n];
        float c1 = dv * dv * x[2 * n + 1] + acc2[2 * n + 1];
        h1[(size_t)n * 64 + lane] = f2bf(fmaxf(c0 * w0 + c1 * w1 + bj, 0.0f));  // post-relu
    }
}

// ------- layer 2 GEMM via MFMA: xw2 = h1 @ W2  (M=NN, K=64, N=64, bf16) -------
// Wave handles 16 nodes/iter. B-frags (all of W2) loop-invariant in 32 VGPRs.
// A-frag: row=lane&15, k-slots (lane>>4)*8+b (same slot map used for B -> any
// hw k-permutation cancels). C/D layout: col=lane&15, row=(lane>>4)*4+reg (m89).
__global__ __launch_bounds__(256) void k_gemm2(const ushort_t* __restrict__ h1,
                                               const ushort_t* __restrict__ W2b,
                                               ushort_t* __restrict__ xw2) {
    int lane = threadIdx.x & 63;
    int wave = (blockIdx.x * blockDim.x + threadIdx.x) >> 6;
    int nwaves = (gridDim.x * blockDim.x) >> 6;
    int col = lane & 15, kg = lane >> 4;

    short8 bfrag[2][4];
#pragma unroll
    for (int t = 0; t < 2; ++t)
#pragma unroll
        for (int j = 0; j < 4; ++j)
#pragma unroll
            for (int b = 0; b < 8; ++b) {
                int k = t * 32 + kg * 8 + b;
                bfrag[t][j][b] = (short)W2b[k * 64 + j * 16 + col];
            }

    const int NT = NN / 16;  // 31250
    for (int tile = wave; tile < NT; tile += nwaves) {
        size_t base = (size_t)tile * 16 * 64;
        const short8* a0p = (const short8*)(h1 + base + (size_t)col * 64 + kg * 8);
        const short8* a1p = (const short8*)(h1 + base + (size_t)col * 64 + 32 + kg * 8);
        short8 a0 = *a0p;
        short8 a1 = *a1p;
        f32x4 acc[4];
#pragma unroll
        for (int j = 0; j < 4; ++j) {
            acc[j] = (f32x4){0.0f, 0.0f, 0.0f, 0.0f};
            acc[j] = __builtin_amdgcn_mfma_f32_16x16x32_bf16(a0, bfrag[0][j], acc[j], 0, 0, 0);
            acc[j] = __builtin_amdgcn_mfma_f32_16x16x32_bf16(a1, bfrag[1][j], acc[j], 0, 0, 0);
        }
        // store: node = tile*16 + kg*4 + r ; channel = j*16 + col
#pragma unroll
        for (int j = 0; j < 4; ++j)
#pragma unroll
            for (int r = 0; r < 4; ++r)
                xw2[base + (size_t)(kg * 4 + r) * 64 + j * 16 + col] = f2bf(acc[j][r]);
    }
}

// ------- layer-2 CSR aggregate + relu + pool atomics (fused) -------
__global__ void k_aggpool(const ushort_t* __restrict__ xw2, const float* __restrict__ b2,
                          const float* __restrict__ dinv, const int* __restrict__ rowoff,
                          const int* __restrict__ esrc, const float* __restrict__ ew,
                          const int* __restrict__ batch, const int* __restrict__ depth,
                          float* __restrict__ sumb, uint_t* __restrict__ mxb,
                          float* __restrict__ cntb) {
    int lane = threadIdx.x & 63;
    int wave = (blockIdx.x * blockDim.x + threadIdx.x) >> 6;
    int nwaves = (gridDim.x * blockDim.x) >> 6;
    float bj = b2[lane];
    for (int n = wave; n < NN; n += nwaves) {
        float dv = dinv[n];
        float acc = dv * dv * bf2f(xw2[(size_t)n * 64 + lane]) + bj;
        int r0 = rowoff[n], r1 = rowoff[n + 1];
        for (int i = r0; i < r1; ++i) {
            int s = esrc[i];
            float w = ew[i];
            acc += w * bf2f(xw2[(size_t)s * 64 + lane]);
        }
        float v = fmaxf(acc, 0.0f);
        int seg = batch[n] * LSEQ + depth[n];
        atomicAdd(&sumb[seg * 64 + lane], v);
        atomicMax(&mxb[seg * 64 + lane], __float_as_uint(v));  // v >= 0
        if (lane == 0) atomicAdd(&cntb[seg], 1.0f);
    }
}

// ---------------- conv1d(k=3,pad=1) + relu + partial mean over L ----------------
__global__ __launch_bounds__(256) void k_conv(const float* __restrict__ sum,
                                              const float* __restrict__ mxf,
                                              const float* __restrict__ cnt,
                                              const float* __restrict__ cw,
                                              const float* __restrict__ cb,
                                              float* __restrict__ pooled) {
    __shared__ float s_seq[66 * 129];
    int b = blockIdx.x >> 3;
    int l0 = (blockIdx.x & 7) * 64;
    int tid = threadIdx.x;
    for (int idx = tid; idx < 66 * 128; idx += 256) {
        int r = idx >> 7, i = idx & 127;
        int l = l0 + r - 1;
        float v = 0.0f;
        if (l >= 0 && l < LSEQ) {
            int seg = b * LSEQ + l;
            if (i < 64) v = sum[seg * 64 + i] / fmaxf(cnt[seg], 1.0f);
            else        v = mxf[seg * 64 + (i - 64)];
        }
        s_seq[r * 129 + i] = v;
    }
    __syncthreads();
    int l_local = tid & 63;
    int wid = tid >> 6;
    for (int rep = 0; rep < 16; ++rep) {
        int c = __builtin_amdgcn_readfirstlane(wid + 4 * rep);
        const float* wc = cw + c * 384;
        float acc = cb[c];
#pragma unroll
        for (int kk = 0; kk < 3; ++kk) {
            const float* sr = s_seq + (l_local + kk) * 129;
#pragma unroll 8
            for (int i = 0; i < 128; ++i)
                acc += sr[i] * wc[i * 3 + kk];
        }
        float y = fmaxf(acc, 0.0f);
#pragma unroll
        for (int off = 32; off; off >>= 1) y += __shfl_xor(y, off, 64);
        if (l_local == 0) atomicAdd(&pooled[b * 64 + c], y);
    }
}

// ---------------- head ----------------
__global__ void k_head(const float* __restrict__ pooled, const float* __restrict__ f1w,
                       const float* __restrict__ f1b, const float* __restrict__ f2w,
                       const float* __restrict__ f2b, float* __restrict__ out) {
    int b = blockIdx.x;
    int j = threadIdx.x;
    const float invL = 1.0f / (float)LSEQ;
    float z = f1b[j];
    for (int c = 0; c < 64; ++c)
        z += (pooled[b * 64 + c] * invL) * f1w[c * 64 + j];
    z = fmaxf(z, 0.0f);
    float v = z * f2w[j];
#pragma unroll
    for (int off = 32; off; off >>= 1) v += __shfl_xor(v, off, 64);
    if (j == 0) out[b] = 1.0f / (1.0f + expf(-(v + f2b[0])));
}

extern "C" void kernel_launch(void* const* d_in, const int* in_sizes, int n_in,
                              void* d_out, int out_size, void* d_ws, size_t ws_size,
                              hipStream_t stream) {
    const float* x     = (const float*)d_in[0];
    const int*   ei    = (const int*)d_in[1];
    const int*   depth = (const int*)d_in[2];
    const int*   batch = (const int*)d_in[3];
    const float* W1    = (const float*)d_in[4];
    const float* b1    = (const float*)d_in[5];
    const float* W2    = (const float*)d_in[6];
    const float* b2    = (const float*)d_in[7];
    const float* cw    = (const float*)d_in[8];
    const float* cb    = (const float*)d_in[9];
    const float* f1w   = (const float*)d_in[10];
    const float* f1b   = (const float*)d_in[11];
    const float* f2w   = (const float*)d_in[12];
    const float* f2b   = (const float*)d_in[13];
    float* out = (float*)d_out;

    // ---- workspace layout (~169 MB, all 16B-aligned chunks) ----
    char* p = (char*)d_ws;
    int*      cnt    = (int*)p;        p += (size_t)NN * 4;
    float*    acc2   = (float*)p;      p += (size_t)NN * 8;
    int*      rowoff = (int*)p;        p += (size_t)(NN + 8) * 4;
    int*      cursor = (int*)p;        p += (size_t)NN * 4;
    float*    dinv   = (float*)p;      p += (size_t)NN * 4;
    int*      esrc   = (int*)p;        p += (size_t)NE * 4;
    float*    ew     = (float*)p;      p += (size_t)NE * 4;
    ushort_t* h1     = (ushort_t*)p;   p += (size_t)NN * 128;
    ushort_t* xw2    = (ushort_t*)p;   p += (size_t)NN * 128;
    float*    sumb   = (float*)p;      p += (size_t)BATCH * LSEQ * 64 * 4;
    uint_t*   mxb    = (uint_t*)p;     p += (size_t)BATCH * LSEQ * 64 * 4;
    float*    cntb   = (float*)p;      p += (size_t)BATCH * LSEQ * 4;
    float*    pool   = (float*)p;      p += (size_t)BATCH * 64 * 4;
    ushort_t* W2b    = (ushort_t*)p;   p += (size_t)64 * 64 * 2;
    int*      bsum   = (int*)p;        // NBLK ints

    const int* src = ei;
    const int* dst = ei + NE;

    // zero: cnt+acc2 (3*NN words) and pool-state region
    k_zero<<<1024, 256, 0, stream>>>((float*)cnt, 3 * NN);
    int zn2 = BATCH * LSEQ * 64 * 2 + BATCH * LSEQ + BATCH * 64;
    k_zero<<<1024, 256, 0, stream>>>(sumb, zn2);

    // degree histogram -> dinv; CSR offsets; W2 bf16
    k_hist<<<(NE + 255) / 256, 256, 0, stream>>>(dst, cnt);
    k_dinv<<<(NN + 255) / 256, 256, 0, stream>>>(cnt, dinv);
    k_w2bf<<<16, 256, 0, stream>>>(W2, W2b);
    k_scan_block<<<NBLK, 256, 0, stream>>>(cnt, bsum);
    k_scan_top<<<1, 512, 0, stream>>>(bsum);
    k_scan_final<<<NBLK, 256, 0, stream>>>(cnt, bsum, rowoff, cursor);

    // CSR reorder + rank-2 layer-1 scatter (2 floats/edge)
    k_reorder<<<(NE + 255) / 256, 256, 0, stream>>>(src, dst, dinv, x, cursor, esrc, ew, acc2);

    // layer-1 dense build (bf16 h1, post-relu)
    k_build1<<<2048, 256, 0, stream>>>(x, W1, b1, dinv, acc2, h1);

    // layer-2 GEMM (MFMA)
    k_gemm2<<<1024, 256, 0, stream>>>(h1, W2b, xw2);

    // layer-2 CSR aggregate + relu + pool (fused)
    k_aggpool<<<2048, 256, 0, stream>>>(xw2, b2, dinv, rowoff, esrc, ew, batch, depth,
                                        sumb, mxb, cntb);

    // conv + partial mean
    k_conv<<<BATCH * 8, 256, 0, stream>>>(sumb, (const float*)mxb, cntb, cw, cb, pool);

    // head
    k_head<<<BATCH, 64, 0, stream>>>(pool, f1w, f1b, f2w, f2b, out);
}

// Round 6
// 725.916 us; speedup vs baseline: 1.9670x; 1.0946x over previous
//
#include <hip/hip_runtime.h>

typedef unsigned short ushort_t;
typedef unsigned int uint_t;
typedef __attribute__((ext_vector_type(8))) short short8;
typedef __attribute__((ext_vector_type(4))) float f32x4;

#define NN 500000
#define NE 1500000
#define BATCH 64
#define LSEQ 512
#define NSEG (BATCH * LSEQ)          // 32768
#define NBLK_E ((NN + 1023) / 1024)  // 489 (edge-CSR scan over NN dst counts)
#define NBLK_S (NSEG / 1024)         // 32  (node-sort scan over NSEG seg counts)

__device__ inline float bf2f(ushort_t u) {
    union { uint_t u; float f; } c; c.u = ((uint_t)u) << 16; return c.f;
}
__device__ inline ushort_t f2bf(float f) {
    union { float f; uint_t u; } c; c.f = f;
    uint_t u = c.u;
    return (ushort_t)((u + 0x7fff + ((u >> 16) & 1)) >> 16);  // RNE
}

// ---------------- zero a 4B-word region ----------------
__global__ void k_zero(float* __restrict__ p, int n) {
    int i = blockIdx.x * blockDim.x + threadIdx.x;
    int stride = gridDim.x * blockDim.x;
    for (; i < n; i += stride) p[i] = 0.0f;
}

// ---------------- histogram of dst ----------------
__global__ void k_hist(const int* __restrict__ dst, int* __restrict__ cnt) {
    int e = blockIdx.x * blockDim.x + threadIdx.x;
    if (e < NE) atomicAdd(&cnt[dst[e]], 1);
}

// ---------------- node seg id + histogram ----------------
__global__ void k_seg(const int* __restrict__ batch, const int* __restrict__ depth,
                      int* __restrict__ segn, int* __restrict__ cnt2) {
    int i = blockIdx.x * blockDim.x + threadIdx.x;
    if (i < NN) {
        int s = batch[i] * LSEQ + depth[i];
        segn[i] = s;
        atomicAdd(&cnt2[s], 1);
    }
}

// ---------------- dinv = rsqrt(deg+1) ----------------
__global__ void k_dinv(const int* __restrict__ cnt, float* __restrict__ dinv) {
    int i = blockIdx.x * blockDim.x + threadIdx.x;
    if (i < NN) dinv[i] = rsqrtf((float)cnt[i] + 1.0f);
}

// ---------------- W2 -> bf16 ----------------
__global__ void k_w2bf(const float* __restrict__ W2, ushort_t* __restrict__ W2b) {
    int i = blockIdx.x * blockDim.x + threadIdx.x;
    if (i < 64 * 64) W2b[i] = f2bf(W2[i]);
}

// ---------------- scan: per-block sums (1024 items/block) ----------------
__global__ __launch_bounds__(256) void k_scan_block(const int* __restrict__ cnt,
                                                    int* __restrict__ bsum, int n) {
    __shared__ int sd[256];
    int blk = blockIdx.x, tid = threadIdx.x;
    int base = blk * 1024 + tid * 4;
    int s = 0;
#pragma unroll
    for (int k = 0; k < 4; ++k) { int i = base + k; if (i < n) s += cnt[i]; }
    sd[tid] = s;
    __syncthreads();
    for (int off = 128; off; off >>= 1) {
        if (tid < off) sd[tid] += sd[tid + off];
        __syncthreads();
    }
    if (tid == 0) bsum[blk] = sd[0];
}

// ---------------- scan: top-level exclusive scan of block sums (nblk <= 512) ----------------
__global__ __launch_bounds__(512) void k_scan_top(int* __restrict__ bsum, int nblk) {
    __shared__ int sd[512];
    int tid = threadIdx.x;
    int v = (tid < nblk) ? bsum[tid] : 0;
    sd[tid] = v;
    __syncthreads();
    for (int off = 1; off < 512; off <<= 1) {
        int t = (tid >= off) ? sd[tid - off] : 0;
        __syncthreads();
        sd[tid] += t;
        __syncthreads();
    }
    if (tid < nblk) bsum[tid] = sd[tid] - v;  // exclusive
}

// ---------------- scan: finalize offsets + cursor ----------------
__global__ __launch_bounds__(256) void k_scan_final(const int* __restrict__ cnt, const int* __restrict__ bsum,
                                                    int* __restrict__ rowoff, int* __restrict__ cursor,
                                                    int n, int total) {
    __shared__ int sd[256];
    int blk = blockIdx.x, tid = threadIdx.x;
    int base = blk * 1024 + tid * 4;
    int loc[4]; int s = 0;
#pragma unroll
    for (int k = 0; k < 4; ++k) { int i = base + k; int c = (i < n) ? cnt[i] : 0; loc[k] = s; s += c; }
    sd[tid] = s;
    __syncthreads();
    for (int off = 1; off < 256; off <<= 1) {
        int t = (tid >= off) ? sd[tid - off] : 0;
        __syncthreads();
        sd[tid] += t;
        __syncthreads();
    }
    int texc = sd[tid] - s + bsum[blk];
#pragma unroll
    for (int k = 0; k < 4; ++k) {
        int i = base + k;
        if (i < n) { int v = texc + loc[k]; rowoff[i] = v; cursor[i] = v; }
    }
    if (blk == 0 && tid == 0) rowoff[n] = total;
}

// ------- reorder edges into CSR (by dst) + rank-2 layer-1 accumulation -------
__global__ void k_reorder(const int* __restrict__ src, const int* __restrict__ dst,
                          const float* __restrict__ dinv, const float* __restrict__ x,
                          int* __restrict__ cursor, int* __restrict__ esrc,
                          float* __restrict__ ew, float* __restrict__ acc2) {
    int e = blockIdx.x * blockDim.x + threadIdx.x;
    if (e >= NE) return;
    int s = src[e], d = dst[e];
    float w = dinv[s] * dinv[d];
    int pos = atomicAdd(&cursor[d], 1);
    esrc[pos] = s;
    ew[pos] = w;
    atomicAdd(&acc2[2 * d],     w * x[2 * s]);
    atomicAdd(&acc2[2 * d + 1], w * x[2 * s + 1]);
}

// ------- reorder node ids by seg -------
__global__ void k_nreorder(const int* __restrict__ segn, int* __restrict__ cursor2,
                           int* __restrict__ nord) {
    int n = blockIdx.x * blockDim.x + threadIdx.x;
    if (n >= NN) return;
    int pos = atomicAdd(&cursor2[segn[n]], 1);
    nord[pos] = n;
}

// ------- layer-1 dense build: h1 = relu(dv^2*(x@W1) + (acc2@W1) + b1)  (bf16) -------
__global__ void k_build1(const float* __restrict__ x, const float* __restrict__ W1,
                         const float* __restrict__ b1, const float* __restrict__ dinv,
                         const float* __restrict__ acc2, ushort_t* __restrict__ h1) {
    int lane = threadIdx.x & 63;
    int wave = (blockIdx.x * blockDim.x + threadIdx.x) >> 6;
    int nwaves = (gridDim.x * blockDim.x) >> 6;
    float w0 = W1[lane], w1 = W1[64 + lane], bj = b1[lane];
    for (int n = wave; n < NN; n += nwaves) {
        float dv = dinv[n];
        float c0 = dv * dv * x[2 * n]     + acc2[2 * n];
        float c1 = dv * dv * x[2 * n + 1] + acc2[2 * n + 1];
        h1[(size_t)n * 64 + lane] = f2bf(fmaxf(c0 * w0 + c1 * w1 + bj, 0.0f));
    }
}

// ------- layer 2 GEMM via MFMA: xw2 = h1 @ W2  (M=NN, K=64, N=64, bf16) -------
__global__ __launch_bounds__(256) void k_gemm2(const ushort_t* __restrict__ h1,
                                               const ushort_t* __restrict__ W2b,
                                               ushort_t* __restrict__ xw2) {
    int lane = threadIdx.x & 63;
    int wave = (blockIdx.x * blockDim.x + threadIdx.x) >> 6;
    int nwaves = (gridDim.x * blockDim.x) >> 6;
    int col = lane & 15, kg = lane >> 4;

    short8 bfrag[2][4];
#pragma unroll
    for (int t = 0; t < 2; ++t)
#pragma unroll
        for (int j = 0; j < 4; ++j)
#pragma unroll
            for (int b = 0; b < 8; ++b) {
                int k = t * 32 + kg * 8 + b;
                bfrag[t][j][b] = (short)W2b[k * 64 + j * 16 + col];
            }

    const int NT = NN / 16;  // 31250
    for (int tile = wave; tile < NT; tile += nwaves) {
        size_t base = (size_t)tile * 16 * 64;
        short8 a0 = *(const short8*)(h1 + base + (size_t)col * 64 + kg * 8);
        short8 a1 = *(const short8*)(h1 + base + (size_t)col * 64 + 32 + kg * 8);
        f32x4 acc[4];
#pragma unroll
        for (int j = 0; j < 4; ++j) {
            acc[j] = (f32x4){0.0f, 0.0f, 0.0f, 0.0f};
            acc[j] = __builtin_amdgcn_mfma_f32_16x16x32_bf16(a0, bfrag[0][j], acc[j], 0, 0, 0);
            acc[j] = __builtin_amdgcn_mfma_f32_16x16x32_bf16(a1, bfrag[1][j], acc[j], 0, 0, 0);
        }
#pragma unroll
        for (int j = 0; j < 4; ++j)
#pragma unroll
            for (int r = 0; r < 4; ++r)
                xw2[base + (size_t)(kg * 4 + r) * 64 + j * 16 + col] = f2bf(acc[j][r]);
    }
}

// ------- layer-2 CSR aggregate + relu + pool (wave per seg, NO atomics) -------
__global__ __launch_bounds__(256) void k_aggpool2(const ushort_t* __restrict__ xw2,
                                                  const float* __restrict__ b2,
                                                  const float* __restrict__ dinv,
                                                  const int* __restrict__ rowoff,
                                                  const int* __restrict__ esrc,
                                                  const float* __restrict__ ew,
                                                  const int* __restrict__ soff,
                                                  const int* __restrict__ nord,
                                                  float* __restrict__ sumb,
                                                  float* __restrict__ mxb,
                                                  float* __restrict__ cntb) {
    int lane = threadIdx.x & 63;
    int seg = (blockIdx.x * blockDim.x + threadIdx.x) >> 6;
    if (seg >= NSEG) return;
    float bj = b2[lane];
    int i0 = soff[seg], i1 = soff[seg + 1];
    float ssum = 0.0f, smax = 0.0f;
    for (int i = i0; i < i1; ++i) {
        int n = nord[i];
        float dv = dinv[n];
        float acc = dv * dv * bf2f(xw2[(size_t)n * 64 + lane]) + bj;
        int r0 = rowoff[n], r1 = rowoff[n + 1];
        for (int e = r0; e < r1; ++e)
            acc += ew[e] * bf2f(xw2[(size_t)esrc[e] * 64 + lane]);
        float v = fmaxf(acc, 0.0f);
        ssum += v;
        smax = fmaxf(smax, v);
    }
    sumb[seg * 64 + lane] = ssum;
    mxb[seg * 64 + lane] = smax;   // 0 for empty seg: matches where(cnt>0, mx, 0)
    if (lane == 0) cntb[seg] = (float)(i1 - i0);
}

// ---------------- conv1d(k=3,pad=1) + relu + partial mean over L ----------------
__global__ __launch_bounds__(256) void k_conv(const float* __restrict__ sum,
                                              const float* __restrict__ mxf,
                                              const float* __restrict__ cnt,
                                              const float* __restrict__ cw,
                                              const float* __restrict__ cb,
                                              float* __restrict__ pooled) {
    __shared__ float s_seq[66 * 129];
    int b = blockIdx.x >> 3;
    int l0 = (blockIdx.x & 7) * 64;
    int tid = threadIdx.x;
    for (int idx = tid; idx < 66 * 128; idx += 256) {
        int r = idx >> 7, i = idx & 127;
        int l = l0 + r - 1;
        float v = 0.0f;
        if (l >= 0 && l < LSEQ) {
            int seg = b * LSEQ + l;
            if (i < 64) v = sum[seg * 64 + i] / fmaxf(cnt[seg], 1.0f);
            else        v = mxf[seg * 64 + (i - 64)];
        }
        s_seq[r * 129 + i] = v;
    }
    __syncthreads();
    int l_local = tid & 63;
    int wid = tid >> 6;
    for (int rep = 0; rep < 16; ++rep) {
        int c = __builtin_amdgcn_readfirstlane(wid + 4 * rep);
        const float* wc = cw + c * 384;
        float acc = cb[c];
#pragma unroll
        for (int kk = 0; kk < 3; ++kk) {
            const float* sr = s_seq + (l_local + kk) * 129;
#pragma unroll 8
            for (int i = 0; i < 128; ++i)
                acc += sr[i] * wc[i * 3 + kk];
        }
        float y = fmaxf(acc, 0.0f);
#pragma unroll
        for (int off = 32; off; off >>= 1) y += __shfl_xor(y, off, 64);
        if (l_local == 0) atomicAdd(&pooled[b * 64 + c], y);
    }
}

// ---------------- head ----------------
__global__ void k_head(const float* __restrict__ pooled, const float* __restrict__ f1w,
                       const float* __restrict__ f1b, const float* __restrict__ f2w,
                       const float* __restrict__ f2b, float* __restrict__ out) {
    int b = blockIdx.x;
    int j = threadIdx.x;
    const float invL = 1.0f / (float)LSEQ;
    float z = f1b[j];
    for (int c = 0; c < 64; ++c)
        z += (pooled[b * 64 + c] * invL) * f1w[c * 64 + j];
    z = fmaxf(z, 0.0f);
    float v = z * f2w[j];
#pragma unroll
    for (int off = 32; off; off >>= 1) v += __shfl_xor(v, off, 64);
    if (j == 0) out[b] = 1.0f / (1.0f + expf(-(v + f2b[0])));
}

extern "C" void kernel_launch(void* const* d_in, const int* in_sizes, int n_in,
                              void* d_out, int out_size, void* d_ws, size_t ws_size,
                              hipStream_t stream) {
    const float* x     = (const float*)d_in[0];
    const int*   ei    = (const int*)d_in[1];
    const int*   depth = (const int*)d_in[2];
    const int*   batch = (const int*)d_in[3];
    const float* W1    = (const float*)d_in[4];
    const float* b1    = (const float*)d_in[5];
    const float* W2    = (const float*)d_in[6];
    const float* b2    = (const float*)d_in[7];
    const float* cw    = (const float*)d_in[8];
    const float* cb    = (const float*)d_in[9];
    const float* f1w   = (const float*)d_in[10];
    const float* f1b   = (const float*)d_in[11];
    const float* f2w   = (const float*)d_in[12];
    const float* f2b   = (const float*)d_in[13];
    float* out = (float*)d_out;

    // ---- workspace layout (~175 MB) ----
    char* p = (char*)d_ws;
    int*      cnt    = (int*)p;        p += (size_t)NN * 4;            // zeroed ┐
    float*    acc2   = (float*)p;      p += (size_t)NN * 8;            //        │ one
    int*      cnt2   = (int*)p;        p += (size_t)NSEG * 4;          //        │ k_zero
    float*    pool   = (float*)p;      p += (size_t)BATCH * 64 * 4;    // zeroed ┘
    int*      rowoff = (int*)p;        p += (size_t)(NN + 8) * 4;
    int*      cursor = (int*)p;        p += (size_t)NN * 4;
    float*    dinv   = (float*)p;      p += (size_t)NN * 4;
    int*      esrc   = (int*)p;        p += (size_t)NE * 4;
    float*    ew     = (float*)p;      p += (size_t)NE * 4;
    int*      segn   = (int*)p;        p += (size_t)NN * 4;
    int*      nord   = (int*)p;        p += (size_t)NN * 4;
    int*      soff   = (int*)p;        p += (size_t)(NSEG + 8) * 4;
    int*      cursor2= (int*)p;        p += (size_t)NSEG * 4;
    ushort_t* h1     = (ushort_t*)p;   p += (size_t)NN * 128;
    ushort_t* xw2    = (ushort_t*)p;   p += (size_t)NN * 128;
    float*    sumb   = (float*)p;      p += (size_t)NSEG * 64 * 4;
    float*    mxb    = (float*)p;      p += (size_t)NSEG * 64 * 4;
    float*    cntb   = (float*)p;      p += (size_t)NSEG * 4;
    ushort_t* W2b    = (ushort_t*)p;   p += (size_t)64 * 64 * 2;
    int*      bsum   = (int*)p;        p += (size_t)512 * 4;
    int*      bsum2  = (int*)p;        // 32 ints

    const int* src = ei;
    const int* dst = ei + NE;

    // zero: cnt + acc2 + cnt2 + pool (contiguous)
    int zn = 3 * NN + NSEG + BATCH * 64;
    k_zero<<<1024, 256, 0, stream>>>((float*)cnt, zn);

    // histograms + dinv + W2 bf16
    k_hist<<<(NE + 255) / 256, 256, 0, stream>>>(dst, cnt);
    k_seg<<<(NN + 255) / 256, 256, 0, stream>>>(batch, depth, segn, cnt2);
    k_dinv<<<(NN + 255) / 256, 256, 0, stream>>>(cnt, dinv);
    k_w2bf<<<16, 256, 0, stream>>>(W2, W2b);

    // edge-CSR offsets
    k_scan_block<<<NBLK_E, 256, 0, stream>>>(cnt, bsum, NN);
    k_scan_top<<<1, 512, 0, stream>>>(bsum, NBLK_E);
    k_scan_final<<<NBLK_E, 256, 0, stream>>>(cnt, bsum, rowoff, cursor, NN, NE);

    // node-sort offsets
    k_scan_block<<<NBLK_S, 256, 0, stream>>>(cnt2, bsum2, NSEG);
    k_scan_top<<<1, 512, 0, stream>>>(bsum2, NBLK_S);
    k_scan_final<<<NBLK_S, 256, 0, stream>>>(cnt2, bsum2, soff, cursor2, NSEG, NN);

    // reorders
    k_reorder<<<(NE + 255) / 256, 256, 0, stream>>>(src, dst, dinv, x, cursor, esrc, ew, acc2);
    k_nreorder<<<(NN + 255) / 256, 256, 0, stream>>>(segn, cursor2, nord);

    // layer-1 dense build (bf16 h1, post-relu)
    k_build1<<<2048, 256, 0, stream>>>(x, W1, b1, dinv, acc2, h1);

    // layer-2 GEMM (MFMA)
    k_gemm2<<<1024, 256, 0, stream>>>(h1, W2b, xw2);

    // layer-2 CSR aggregate + relu + pool (atomic-free)
    k_aggpool2<<<NSEG / 4, 256, 0, stream>>>(xw2, b2, dinv, rowoff, esrc, ew, soff, nord,
                                             sumb, mxb, cntb);

    // conv + partial mean
    k_conv<<<BATCH * 8, 256, 0, stream>>>(sumb, mxb, cntb, cw, cb, pool);

    // head
    k_head<<<BATCH, 64, 0, stream>>>(pool, f1w, f1b, f2w, f2b, out);
}

// Round 7
// 671.214 us; speedup vs baseline: 2.1273x; 1.0815x over previous
//
#include <hip/hip_runtime.h>

typedef unsigned short ushort_t;
typedef unsigned int uint_t;
typedef __attribute__((ext_vector_type(8))) short short8;
typedef __attribute__((ext_vector_type(4))) float f32x4;

#define NN 500000
#define NE 1500000
#define BATCH 64
#define LSEQ 512
#define NSEG (BATCH * LSEQ)          // 32768
#define NBLK_E ((NN + 1023) / 1024)  // 489
#define NBLK_S (NSEG / 1024)         // 32

__device__ inline float bf2f(ushort_t u) {
    union { uint_t u; float f; } c; c.u = ((uint_t)u) << 16; return c.f;
}
__device__ inline ushort_t f2bf(float f) {
    union { float f; uint_t u; } c; c.f = f;
    uint_t u = c.u;
    return (ushort_t)((u + 0x7fff + ((u >> 16) & 1)) >> 16);  // RNE
}
__device__ inline int imax(int a, int b) { return a > b ? a : b; }

// ---------------- zero a 4B-word region ----------------
__global__ void k_zero(float* __restrict__ p, int n) {
    int i = blockIdx.x * blockDim.x + threadIdx.x;
    int stride = gridDim.x * blockDim.x;
    for (; i < n; i += stride) p[i] = 0.0f;
}

// ---------------- fused: dst histogram + node seg id/histogram ----------------
__global__ void k_hist2(const int* __restrict__ dst, const int* __restrict__ batch,
                        const int* __restrict__ depth, int* __restrict__ cnt,
                        int* __restrict__ segn, int* __restrict__ cnt2) {
    int t = blockIdx.x * blockDim.x + threadIdx.x;
    if (t < NE) {
        atomicAdd(&cnt[dst[t]], 1);
        if (t < NN) {
            int s = batch[t] * LSEQ + depth[t];
            segn[t] = s;
            atomicAdd(&cnt2[s], 1);
        }
    }
}

// ---------------- fused: dinv = rsqrt(deg+1) + W2 -> bf16 ----------------
__global__ void k_prep(const int* __restrict__ cnt, float* __restrict__ dinv,
                       const float* __restrict__ W2, ushort_t* __restrict__ W2b) {
    int i = blockIdx.x * blockDim.x + threadIdx.x;
    if (i < NN) dinv[i] = rsqrtf((float)cnt[i] + 1.0f);
    if (i < 64 * 64) W2b[i] = f2bf(W2[i]);
}

// ---------------- fused scans (edge-CSR over NN + node-sort over NSEG) ----------------
__device__ void scan_block_dev(const int* __restrict__ cnt, int* __restrict__ bsum,
                               int n, int blk, int* sd) {
    int tid = threadIdx.x;
    int base = blk * 1024 + tid * 4;
    int s = 0;
#pragma unroll
    for (int k = 0; k < 4; ++k) { int i = base + k; if (i < n) s += cnt[i]; }
    sd[tid] = s;
    __syncthreads();
    for (int off = 128; off; off >>= 1) {
        if (tid < off) sd[tid] += sd[tid + off];
        __syncthreads();
    }
    if (tid == 0) bsum[blk] = sd[0];
}

__global__ __launch_bounds__(256) void k_scan_block_f(const int* __restrict__ cnt, int* __restrict__ bsum,
                                                      const int* __restrict__ cnt2, int* __restrict__ bsum2) {
    __shared__ int sd[256];
    int blk = blockIdx.x;
    if (blk < NBLK_E) scan_block_dev(cnt, bsum, NN, blk, sd);
    else              scan_block_dev(cnt2, bsum2, NSEG, blk - NBLK_E, sd);
}

__device__ void scan_top_dev(int* __restrict__ b, int nblk, int* sd) {
    int tid = threadIdx.x;
    __syncthreads();
    int v = (tid < nblk) ? b[tid] : 0;
    sd[tid] = v;
    __syncthreads();
    for (int off = 1; off < 512; off <<= 1) {
        int t = (tid >= off) ? sd[tid - off] : 0;
        __syncthreads();
        sd[tid] += t;
        __syncthreads();
    }
    if (tid < nblk) b[tid] = sd[tid] - v;  // exclusive
}

__global__ __launch_bounds__(512) void k_scan_top_f(int* __restrict__ bsum, int* __restrict__ bsum2) {
    __shared__ int sd[512];
    scan_top_dev(bsum, NBLK_E, sd);
    scan_top_dev(bsum2, NBLK_S, sd);
}

__device__ void scan_final_dev(const int* __restrict__ cnt, const int* __restrict__ bsum,
                               int* __restrict__ rowoff, int* __restrict__ cursor,
                               int n, int total, int blk, int* sd) {
    int tid = threadIdx.x;
    int base = blk * 1024 + tid * 4;
    int loc[4]; int s = 0;
#pragma unroll
    for (int k = 0; k < 4; ++k) { int i = base + k; int c = (i < n) ? cnt[i] : 0; loc[k] = s; s += c; }
    sd[tid] = s;
    __syncthreads();
    for (int off = 1; off < 256; off <<= 1) {
        int t = (tid >= off) ? sd[tid - off] : 0;
        __syncthreads();
        sd[tid] += t;
        __syncthreads();
    }
    int texc = sd[tid] - s + bsum[blk];
#pragma unroll
    for (int k = 0; k < 4; ++k) {
        int i = base + k;
        if (i < n) { int v = texc + loc[k]; rowoff[i] = v; cursor[i] = v; }
    }
    if (blk == 0 && tid == 0) rowoff[n] = total;
}

__global__ __launch_bounds__(256) void k_scan_final_f(const int* __restrict__ cnt, const int* __restrict__ bsum,
                                                      int* __restrict__ rowoff, int* __restrict__ cursor,
                                                      const int* __restrict__ cnt2, const int* __restrict__ bsum2,
                                                      int* __restrict__ soff, int* __restrict__ cursor2) {
    __shared__ int sd[256];
    int blk = blockIdx.x;
    if (blk < NBLK_E) scan_final_dev(cnt, bsum, rowoff, cursor, NN, NE, blk, sd);
    else              scan_final_dev(cnt2, bsum2, soff, cursor2, NSEG, NN, blk - NBLK_E, sd);
}

// ------- reorder edges into CSR (by dst): packed {src, w} 8 B stores, no acc2 -------
__global__ void k_reorder(const int* __restrict__ src, const int* __restrict__ dst,
                          const float* __restrict__ dinv,
                          int* __restrict__ cursor, uint2* __restrict__ ep) {
    int e = blockIdx.x * blockDim.x + threadIdx.x;
    if (e >= NE) return;
    int s = src[e], d = dst[e];
    float w = dinv[s] * dinv[d];
    int pos = atomicAdd(&cursor[d], 1);
    ep[pos] = make_uint2((uint_t)s, __float_as_uint(w));
}

// ------- reorder node ids by seg -------
__global__ void k_nreorder(const int* __restrict__ segn, int* __restrict__ cursor2,
                           int* __restrict__ nord) {
    int n = blockIdx.x * blockDim.x + threadIdx.x;
    if (n >= NN) return;
    int pos = atomicAdd(&cursor2[segn[n]], 1);
    nord[pos] = n;
}

// ------- layer-1: CSR x-aggregation (exact f32) + dense build, 2-node interleave -------
// h1 = relu( W1^T (dv^2 x[n] + sum w x[src]) + b1 ), bf16
__global__ void k_build1(const float* __restrict__ x, const float* __restrict__ W1,
                         const float* __restrict__ b1, const float* __restrict__ dinv,
                         const int* __restrict__ rowoff, const uint2* __restrict__ ep,
                         ushort_t* __restrict__ h1) {
    int lane = threadIdx.x & 63;
    int wave = (blockIdx.x * blockDim.x + threadIdx.x) >> 6;
    int nwaves = (gridDim.x * blockDim.x) >> 6;
    const float2* x2 = (const float2*)x;
    float w0 = W1[lane], w1 = W1[64 + lane], bj = b1[lane];
    for (int n0 = wave * 2; n0 < NN; n0 += nwaves * 2) {
        int n1 = n0 + 1;  // NN even
        float dA = dinv[n0], dB = dinv[n1];
        float2 xA = x2[n0], xB = x2[n1];
        float a0 = dA * dA * xA.x, a1 = dA * dA * xA.y;
        float c0 = dB * dB * xB.x, c1 = dB * dB * xB.y;
        int rA = rowoff[n0], rB = rowoff[n1], rE = rowoff[n0 + 2];
        int lA = rB - rA, lB = rE - rB;
        int len = imax(lA, lB);
        for (int k = 0; k < len; ++k) {
            if (k < lA) {
                uint2 p = ep[rA + k];
                float w = __uint_as_float(p.y);
                float2 xv = x2[p.x];
                a0 += w * xv.x; a1 += w * xv.y;
            }
            if (k < lB) {
                uint2 p = ep[rB + k];
                float w = __uint_as_float(p.y);
                float2 xv = x2[p.x];
                c0 += w * xv.x; c1 += w * xv.y;
            }
        }
        h1[(size_t)n0 * 64 + lane] = f2bf(fmaxf(a0 * w0 + a1 * w1 + bj, 0.0f));
        h1[(size_t)n1 * 64 + lane] = f2bf(fmaxf(c0 * w0 + c1 * w1 + bj, 0.0f));
    }
}

// ------- layer 2 GEMM via MFMA: xw2 = h1 @ W2  (M=NN, K=64, N=64, bf16) -------
__global__ __launch_bounds__(256) void k_gemm2(const ushort_t* __restrict__ h1,
                                               const ushort_t* __restrict__ W2b,
                                               ushort_t* __restrict__ xw2) {
    int lane = threadIdx.x & 63;
    int wave = (blockIdx.x * blockDim.x + threadIdx.x) >> 6;
    int nwaves = (gridDim.x * blockDim.x) >> 6;
    int col = lane & 15, kg = lane >> 4;

    short8 bfrag[2][4];
#pragma unroll
    for (int t = 0; t < 2; ++t)
#pragma unroll
        for (int j = 0; j < 4; ++j)
#pragma unroll
            for (int b = 0; b < 8; ++b) {
                int k = t * 32 + kg * 8 + b;
                bfrag[t][j][b] = (short)W2b[k * 64 + j * 16 + col];
            }

    const int NT = NN / 16;  // 31250
    for (int tile = wave; tile < NT; tile += nwaves) {
        size_t base = (size_t)tile * 16 * 64;
        short8 a0 = *(const short8*)(h1 + base + (size_t)col * 64 + kg * 8);
        short8 a1 = *(const short8*)(h1 + base + (size_t)col * 64 + 32 + kg * 8);
        f32x4 acc[4];
#pragma unroll
        for (int j = 0; j < 4; ++j) {
            acc[j] = (f32x4){0.0f, 0.0f, 0.0f, 0.0f};
            acc[j] = __builtin_amdgcn_mfma_f32_16x16x32_bf16(a0, bfrag[0][j], acc[j], 0, 0, 0);
            acc[j] = __builtin_amdgcn_mfma_f32_16x16x32_bf16(a1, bfrag[1][j], acc[j], 0, 0, 0);
        }
#pragma unroll
        for (int j = 0; j < 4; ++j)
#pragma unroll
            for (int r = 0; r < 4; ++r)
                xw2[base + (size_t)(kg * 4 + r) * 64 + j * 16 + col] = f2bf(acc[j][r]);
    }
}

// ------- layer-2 CSR aggregate + relu + pool (wave per seg, 4-node interleave) -------
__global__ __launch_bounds__(256) void k_aggpool2(const ushort_t* __restrict__ xw2,
                                                  const float* __restrict__ b2,
                                                  const float* __restrict__ dinv,
                                                  const int* __restrict__ rowoff,
                                                  const uint2* __restrict__ ep,
                                                  const int* __restrict__ soff,
                                                  const int* __restrict__ nord,
                                                  float* __restrict__ sumb,
                                                  float* __restrict__ mxb,
                                                  float* __restrict__ cntb) {
    int lane = threadIdx.x & 63;
    int seg = (blockIdx.x * blockDim.x + threadIdx.x) >> 6;
    if (seg >= NSEG) return;
    float bj = b2[lane];
    int i0 = soff[seg], i1 = soff[seg + 1];
    float ssum = 0.0f, smax = 0.0f;
    int i = i0;
    for (; i + 4 <= i1; i += 4) {
        int nA = nord[i], nB = nord[i + 1], nC = nord[i + 2], nD = nord[i + 3];
        float dA = dinv[nA], dB = dinv[nB], dC = dinv[nC], dD = dinv[nD];
        float aA = dA * dA * bf2f(xw2[(size_t)nA * 64 + lane]) + bj;
        float aB = dB * dB * bf2f(xw2[(size_t)nB * 64 + lane]) + bj;
        float aC = dC * dC * bf2f(xw2[(size_t)nC * 64 + lane]) + bj;
        float aD = dD * dD * bf2f(xw2[(size_t)nD * 64 + lane]) + bj;
        int rA = rowoff[nA], lA = rowoff[nA + 1] - rA;
        int rB = rowoff[nB], lB = rowoff[nB + 1] - rB;
        int rC = rowoff[nC], lC = rowoff[nC + 1] - rC;
        int rD = rowoff[nD], lD = rowoff[nD + 1] - rD;
        int len = imax(imax(lA, lB), imax(lC, lD));
        for (int k = 0; k < len; ++k) {
            if (k < lA) { uint2 p = ep[rA + k]; aA += __uint_as_float(p.y) * bf2f(xw2[(size_t)p.x * 64 + lane]); }
            if (k < lB) { uint2 p = ep[rB + k]; aB += __uint_as_float(p.y) * bf2f(xw2[(size_t)p.x * 64 + lane]); }
            if (k < lC) { uint2 p = ep[rC + k]; aC += __uint_as_float(p.y) * bf2f(xw2[(size_t)p.x * 64 + lane]); }
            if (k < lD) { uint2 p = ep[rD + k]; aD += __uint_as_float(p.y) * bf2f(xw2[(size_t)p.x * 64 + lane]); }
        }
        float vA = fmaxf(aA, 0.0f), vB = fmaxf(aB, 0.0f);
        float vC = fmaxf(aC, 0.0f), vD = fmaxf(aD, 0.0f);
        ssum += (vA + vB) + (vC + vD);
        smax = fmaxf(smax, fmaxf(fmaxf(vA, vB), fmaxf(vC, vD)));
    }
    for (; i < i1; ++i) {
        int n = nord[i];
        float dv = dinv[n];
        float acc = dv * dv * bf2f(xw2[(size_t)n * 64 + lane]) + bj;
        int r0 = rowoff[n], r1 = rowoff[n + 1];
        for (int e = r0; e < r1; ++e) {
            uint2 p = ep[e];
            acc += __uint_as_float(p.y) * bf2f(xw2[(size_t)p.x * 64 + lane]);
        }
        float v = fmaxf(acc, 0.0f);
        ssum += v;
        smax = fmaxf(smax, v);
    }
    sumb[seg * 64 + lane] = ssum;
    mxb[seg * 64 + lane] = smax;   // 0 for empty seg: matches where(cnt>0, mx, 0)
    if (lane == 0) cntb[seg] = (float)(i1 - i0);
}

// ---------------- conv1d(k=3,pad=1) + relu + partial mean over L ----------------
__global__ __launch_bounds__(256) void k_conv(const float* __restrict__ sum,
                                              const float* __restrict__ mxf,
                                              const float* __restrict__ cnt,
                                              const float* __restrict__ cw,
                                              const float* __restrict__ cb,
                                              float* __restrict__ pooled) {
    __shared__ float s_seq[66 * 129];
    int b = blockIdx.x >> 3;
    int l0 = (blockIdx.x & 7) * 64;
    int tid = threadIdx.x;
    for (int idx = tid; idx < 66 * 128; idx += 256) {
        int r = idx >> 7, i = idx & 127;
        int l = l0 + r - 1;
        float v = 0.0f;
        if (l >= 0 && l < LSEQ) {
            int seg = b * LSEQ + l;
            if (i < 64) v = sum[seg * 64 + i] / fmaxf(cnt[seg], 1.0f);
            else        v = mxf[seg * 64 + (i - 64)];
        }
        s_seq[r * 129 + i] = v;
    }
    __syncthreads();
    int l_local = tid & 63;
    int wid = tid >> 6;
    for (int rep = 0; rep < 16; ++rep) {
        int c = __builtin_amdgcn_readfirstlane(wid + 4 * rep);
        const float* wc = cw + c * 384;
        float acc = cb[c];
#pragma unroll
        for (int kk = 0; kk < 3; ++kk) {
            const float* sr = s_seq + (l_local + kk) * 129;
#pragma unroll 8
            for (int i = 0; i < 128; ++i)
                acc += sr[i] * wc[i * 3 + kk];
        }
        float y = fmaxf(acc, 0.0f);
#pragma unroll
        for (int off = 32; off; off >>= 1) y += __shfl_xor(y, off, 64);
        if (l_local == 0) atomicAdd(&pooled[b * 64 + c], y);
    }
}

// ---------------- head ----------------
__global__ void k_head(const float* __restrict__ pooled, const float* __restrict__ f1w,
                       const float* __restrict__ f1b, const float* __restrict__ f2w,
                       const float* __restrict__ f2b, float* __restrict__ out) {
    int b = blockIdx.x;
    int j = threadIdx.x;
    const float invL = 1.0f / (float)LSEQ;
    float z = f1b[j];
    for (int c = 0; c < 64; ++c)
        z += (pooled[b * 64 + c] * invL) * f1w[c * 64 + j];
    z = fmaxf(z, 0.0f);
    float v = z * f2w[j];
#pragma unroll
    for (int off = 32; off; off >>= 1) v += __shfl_xor(v, off, 64);
    if (j == 0) out[b] = 1.0f / (1.0f + expf(-(v + f2b[0])));
}

extern "C" void kernel_launch(void* const* d_in, const int* in_sizes, int n_in,
                              void* d_out, int out_size, void* d_ws, size_t ws_size,
                              hipStream_t stream) {
    const float* x     = (const float*)d_in[0];
    const int*   ei    = (const int*)d_in[1];
    const int*   depth = (const int*)d_in[2];
    const int*   batch = (const int*)d_in[3];
    const float* W1    = (const float*)d_in[4];
    const float* b1    = (const float*)d_in[5];
    const float* W2    = (const float*)d_in[6];
    const float* b2    = (const float*)d_in[7];
    const float* cw    = (const float*)d_in[8];
    const float* cb    = (const float*)d_in[9];
    const float* f1w   = (const float*)d_in[10];
    const float* f1b   = (const float*)d_in[11];
    const float* f2w   = (const float*)d_in[12];
    const float* f2b   = (const float*)d_in[13];
    float* out = (float*)d_out;

    // ---- workspace layout (~169 MB), each chunk 16B-aligned ----
    char* p = (char*)d_ws;
    auto bump = [&p](size_t bytes) { char* r = p; p += (bytes + 15) & ~(size_t)15; return r; };
    int*      cnt    = (int*)bump((size_t)NN * 4);          // zeroed ┐
    int*      cnt2   = (int*)bump((size_t)NSEG * 4);        //        │ one k_zero
    float*    pool   = (float*)bump((size_t)BATCH * 64 * 4);// zeroed ┘
    int*      rowoff = (int*)bump((size_t)(NN + 8) * 4);
    int*      cursor = (int*)bump((size_t)NN * 4);
    float*    dinv   = (float*)bump((size_t)NN * 4);
    int*      segn   = (int*)bump((size_t)NN * 4);
    int*      nord   = (int*)bump((size_t)NN * 4);
    int*      soff   = (int*)bump((size_t)(NSEG + 8) * 4);
    int*      cursor2= (int*)bump((size_t)NSEG * 4);
    uint2*    ep     = (uint2*)bump((size_t)NE * 8);
    ushort_t* h1     = (ushort_t*)bump((size_t)NN * 128);
    ushort_t* xw2    = (ushort_t*)bump((size_t)NN * 128);
    float*    sumb   = (float*)bump((size_t)NSEG * 64 * 4);
    float*    mxb    = (float*)bump((size_t)NSEG * 64 * 4);
    float*    cntb   = (float*)bump((size_t)NSEG * 4);
    ushort_t* W2b    = (ushort_t*)bump((size_t)64 * 64 * 2);
    int*      bsum   = (int*)bump((size_t)512 * 4);
    int*      bsum2  = (int*)bump((size_t)64 * 4);

    const int* src = ei;
    const int* dst = ei + NE;

    // zero: cnt + cnt2 + pool (contiguous by layout)
    int zn = NN + NSEG + BATCH * 64 + 16;  // +pad slack
    k_zero<<<512, 256, 0, stream>>>((float*)cnt, zn);

    // fused histograms; dinv + W2 bf16
    k_hist2<<<(NE + 255) / 256, 256, 0, stream>>>(dst, batch, depth, cnt, segn, cnt2);
    k_prep<<<(NN + 255) / 256, 256, 0, stream>>>(cnt, dinv, W2, W2b);

    // fused scans: edge-CSR offsets + node-sort offsets
    k_scan_block_f<<<NBLK_E + NBLK_S, 256, 0, stream>>>(cnt, bsum, cnt2, bsum2);
    k_scan_top_f<<<1, 512, 0, stream>>>(bsum, bsum2);
    k_scan_final_f<<<NBLK_E + NBLK_S, 256, 0, stream>>>(cnt, bsum, rowoff, cursor,
                                                        cnt2, bsum2, soff, cursor2);

    // reorders
    k_reorder<<<(NE + 255) / 256, 256, 0, stream>>>(src, dst, dinv, cursor, ep);
    k_nreorder<<<(NN + 255) / 256, 256, 0, stream>>>(segn, cursor2, nord);

    // layer-1: CSR aggregate x + dense build (bf16 h1, post-relu)
    k_build1<<<2048, 256, 0, stream>>>(x, W1, b1, dinv, rowoff, ep, h1);

    // layer-2 GEMM (MFMA)
    k_gemm2<<<1024, 256, 0, stream>>>(h1, W2b, xw2);

    // layer-2 CSR aggregate + relu + pool (atomic-free, 4-way MLP)
    k_aggpool2<<<NSEG / 4, 256, 0, stream>>>(xw2, b2, dinv, rowoff, ep, soff, nord,
                                             sumb, mxb, cntb);

    // conv + partial mean
    k_conv<<<BATCH * 8, 256, 0, stream>>>(sumb, mxb, cntb, cw, cb, pool);

    // head
    k_head<<<BATCH, 64, 0, stream>>>(pool, f1w, f1b, f2w, f2b, out);
}